// Round 1
// baseline (101.006 us; speedup 1.0000x reference)
//
#include <hip/hip_runtime.h>

#define NDIM 2048
#define KDIM 512
#define DDIM 64
#define PAD 68   // 64 + 4: keeps float4 alignment, breaks power-of-2 bank stride

__device__ __forceinline__ float sigf(float x) {
    // sigmoid(x) = 1/(1+exp(-x)); exp(-x) = exp2(-x*log2(e))
    return __builtin_amdgcn_rcpf(1.0f + __builtin_amdgcn_exp2f(x * -1.44269504088896340736f));
}

// ---------------------------------------------------------------------------
// zkern: grid 256 blocks x 128 threads. Block b computes rows i0=b*8..i0+7 of
// z = x@W, plus zw = z*w3b, a = relu(z)@u, b = relu(z)@v.
// u = W2[:64]@w3a, v = W2[64:]@w3a computed redundantly per block (cheap).
// ---------------------------------------------------------------------------
__global__ __launch_bounds__(128) void zkern(
    const float* __restrict__ x, const float* __restrict__ W,
    const float* __restrict__ W2, const float* __restrict__ W3,
    float* __restrict__ A, float* __restrict__ Bv,
    float* __restrict__ Z, float* __restrict__ ZW)
{
    __shared__ float4 xs4[8 * 128];   // 8 rows x 512 cols f32
    __shared__ float us[64], vs[64];
    float* xs = (float*)xs4;

    const int t  = threadIdx.x;
    const int i0 = blockIdx.x * 8;

    // ---- u/v: wave 0 computes u, wave 1 computes v (wave-uniform branch) ----
    {
        const int k = t & 63;
        const float* wrow = W2 + (size_t)((t < 64 ? k : 64 + k)) * 64;
        float s = 0.f;
        #pragma unroll
        for (int n4 = 0; n4 < 16; ++n4) {
            float4 w2v = ((const float4*)wrow)[n4];
            float4 w3v = ((const float4*)W3)[n4];
            s += w2v.x * w3v.x + w2v.y * w3v.y + w2v.z * w3v.z + w2v.w * w3v.w;
        }
        if (t < 64) us[k] = s; else vs[k] = s;
    }

    // ---- stage x tile (8 x 512 f32), coalesced float4 ----
    #pragma unroll
    for (int chunk = 0; chunk < 8; ++chunk) {
        int idx = chunk * 128 + t;          // float4 index 0..1023
        int row = idx >> 7;                 // 0..7
        int c4  = idx & 127;
        xs4[row * 128 + c4] = ((const float4*)(x + (size_t)(i0 + row) * KDIM))[c4];
    }
    __syncthreads();

    const int tx = t & 15;
    const int w  = t >> 4;                  // row within tile 0..7
    const int c  = tx * 4;                  // 4 cols per thread

    float4 acc = {0.f, 0.f, 0.f, 0.f};
    const float* xrow = xs + w * KDIM;
    #pragma unroll 8
    for (int k = 0; k < KDIM; ++k) {
        float  xv = xrow[k];                                // LDS broadcast
        float4 wv = *(const float4*)(W + (size_t)k * 64 + c); // coalesced, L1/L2-hot
        acc.x += xv * wv.x; acc.y += xv * wv.y;
        acc.z += xv * wv.z; acc.w += xv * wv.w;
    }

    const int row = i0 + w;
    *(float4*)(Z + (size_t)row * 64 + c) = acc;

    float4 w3b = *(const float4*)(W3 + 64 + c);
    float4 zw  = {acc.x * w3b.x, acc.y * w3b.y, acc.z * w3b.z, acc.w * w3b.w};
    *(float4*)(ZW + (size_t)row * 64 + c) = zw;

    float4 rz = {fmaxf(acc.x, 0.f), fmaxf(acc.y, 0.f),
                 fmaxf(acc.z, 0.f), fmaxf(acc.w, 0.f)};
    float4 u4 = *(const float4*)(us + c);
    float4 v4 = *(const float4*)(vs + c);
    float pa = rz.x * u4.x + rz.y * u4.y + rz.z * u4.z + rz.w * u4.w;
    float pb = rz.x * v4.x + rz.y * v4.y + rz.z * v4.z + rz.w * v4.w;
    #pragma unroll
    for (int m = 1; m < 16; m <<= 1) {      // reduce over the 16 tx lanes
        pa += __shfl_xor(pa, m, 64);
        pb += __shfl_xor(pb, m, 64);
    }
    if (tx == 0) { A[row] = pa; Bv[row] = pb; }
}

// ---------------------------------------------------------------------------
// mainkern: grid (32,32) x 256 threads. Block computes 64x64 output tile:
// out[i,j] = sig(sig(a_i + b_j + sum_d Z[i,d]*ZW[j,d])).
// Tiles staged TRANSPOSED [d][row] with pad 68 -> inner loop is two
// conflict-free ds_read_b128 + 16 FMA per d (FMA-bound).
// ---------------------------------------------------------------------------
__global__ __launch_bounds__(256) void mainkern(
    const float* __restrict__ Z, const float* __restrict__ ZW,
    const float* __restrict__ A, const float* __restrict__ Bv,
    float* __restrict__ out)
{
    __shared__ float4 sZ4[DDIM * (PAD / 4)];   // 64 x 68 f32, [d][row]
    __shared__ float4 sW4[DDIM * (PAD / 4)];
    float* sZ = (float*)sZ4;
    float* sW = (float*)sW4;

    const int t  = threadIdx.x;
    const int i0 = blockIdx.y * 64;
    const int j0 = blockIdx.x * 64;

    const float4* zsrc = (const float4*)(Z  + (size_t)i0 * 64);
    const float4* wsrc = (const float4*)(ZW + (size_t)j0 * 64);

    // stage + transpose: coalesced float4 global reads, scalar LDS stores
    #pragma unroll
    for (int chunk = 0; chunk < 4; ++chunk) {
        int idx = chunk * 256 + t;         // float4 index 0..1023
        int row = idx >> 4;                // 0..63
        int d   = (idx & 15) << 2;         // 0..60
        float4 g = zsrc[idx];
        sZ[(d + 0) * PAD + row] = g.x;
        sZ[(d + 1) * PAD + row] = g.y;
        sZ[(d + 2) * PAD + row] = g.z;
        sZ[(d + 3) * PAD + row] = g.w;
        float4 h = wsrc[idx];
        sW[(d + 0) * PAD + row] = h.x;
        sW[(d + 1) * PAD + row] = h.y;
        sW[(d + 2) * PAD + row] = h.z;
        sW[(d + 3) * PAD + row] = h.w;
    }
    __syncthreads();

    const int tx = t & 15;                 // 4 cols  j0+4*tx..+3
    const int ty = t >> 4;                 // 4 rows  i0+4*ty..+3

    float acc[4][4] = {{0.f}};
    #pragma unroll 8
    for (int d = 0; d < DDIM; ++d) {
        float4 zr = *(const float4*)(sZ + d * PAD + 4 * ty);  // rows (broadcast x16)
        float4 wc = *(const float4*)(sW + d * PAD + 4 * tx);  // cols (2-way, free)
        acc[0][0] += zr.x * wc.x; acc[0][1] += zr.x * wc.y;
        acc[0][2] += zr.x * wc.z; acc[0][3] += zr.x * wc.w;
        acc[1][0] += zr.y * wc.x; acc[1][1] += zr.y * wc.y;
        acc[1][2] += zr.y * wc.z; acc[1][3] += zr.y * wc.w;
        acc[2][0] += zr.z * wc.x; acc[2][1] += zr.z * wc.y;
        acc[2][2] += zr.z * wc.z; acc[2][3] += zr.z * wc.w;
        acc[3][0] += zr.w * wc.x; acc[3][1] += zr.w * wc.y;
        acc[3][2] += zr.w * wc.z; acc[3][3] += zr.w * wc.w;
    }

    const int irow = i0 + ty * 4;
    const int jcol = j0 + tx * 4;
    float4 b4 = *(const float4*)(Bv + jcol);
    #pragma unroll
    for (int r = 0; r < 4; ++r) {
        float ar = A[irow + r];
        float4 o;
        o.x = sigf(sigf(ar + b4.x + acc[r][0]));
        o.y = sigf(sigf(ar + b4.y + acc[r][1]));
        o.z = sigf(sigf(ar + b4.z + acc[r][2]));
        o.w = sigf(sigf(ar + b4.w + acc[r][3]));
        *(float4*)(out + (size_t)(irow + r) * NDIM + jcol) = o;
    }
}

extern "C" void kernel_launch(void* const* d_in, const int* in_sizes, int n_in,
                              void* d_out, int out_size, void* d_ws, size_t ws_size,
                              hipStream_t stream)
{
    const float* x  = (const float*)d_in[0];   // 2048 x 512
    const float* W  = (const float*)d_in[1];   // 512 x 64
    const float* W2 = (const float*)d_in[2];   // 128 x 64
    const float* W3 = (const float*)d_in[3];   // 128 x 1
    float* out = (float*)d_out;                // 2048 x 2048 f32

    float* ws = (float*)d_ws;
    float* A  = ws;                            // 2048
    float* Bv = ws + 2048;                     // 2048
    float* Z  = ws + 4096;                     // 2048 x 64
    float* ZW = ws + 4096 + NDIM * DDIM;       // 2048 x 64  (~1.05 MB total)

    zkern<<<dim3(256), dim3(128), 0, stream>>>(x, W, W2, W3, A, Bv, Z, ZW);
    mainkern<<<dim3(32, 32), dim3(256), 0, stream>>>(Z, ZW, A, Bv, out);
}

// Round 2
// 80.527 us; speedup vs baseline: 1.2543x; 1.2543x over previous
//
#include <hip/hip_runtime.h>

#define NDIM 2048
#define KD 512
#define DD 64
#define LSTR 72   // LDS row stride in bf16 (144 B): 16B-aligned, bank-balanced

typedef short bf16x8 __attribute__((ext_vector_type(8)));
typedef float f32x4  __attribute__((ext_vector_type(4)));

__device__ __forceinline__ float sigf(float x) {
    return __builtin_amdgcn_rcpf(1.0f + __builtin_amdgcn_exp2f(x * -1.44269504088896f));
}
__device__ __forceinline__ unsigned short f2bf(float f) {
    union { float f; unsigned u; } c; c.f = f;
    unsigned r = c.u + 0x7FFF + ((c.u >> 16) & 1);   // RNE
    return (unsigned short)(r >> 16);
}

// ---------------------------------------------------------------------------
// zkern: 256 blocks x 256 threads, 8 rows/block, split-K(2).
// Emits A=relu(z)@u, Bv=relu(z)@v (f32), Zb=bf16(z), ZWb=bf16(z*w3b).
// ---------------------------------------------------------------------------
__global__ __launch_bounds__(256) void zkern(
    const float* __restrict__ x, const float* __restrict__ W,
    const float* __restrict__ W2, const float* __restrict__ W3,
    float* __restrict__ A, float* __restrict__ Bv,
    unsigned short* __restrict__ Zb, unsigned short* __restrict__ ZWb)
{
    __shared__ float4 xs4[8 * 128];          // 8 rows x 512 f32
    __shared__ float  us[64], vs[64];
    __shared__ float4 part[128];             // split-K partials
    const float* xs = (const float*)xs4;
    const int t  = threadIdx.x;
    const int i0 = blockIdx.x * 8;

    // u = W2[:64]@w3a (wave0), v = W2[64:]@w3a (wave1)
    if (t < 128) {
        const int k = t & 63;
        const float* wrow = W2 + (size_t)(t < 64 ? k : 64 + k) * 64;
        float s = 0.f;
        #pragma unroll
        for (int n4 = 0; n4 < 16; ++n4) {
            float4 a = ((const float4*)wrow)[n4];
            float4 b = ((const float4*)W3)[n4];
            s += a.x * b.x + a.y * b.y + a.z * b.z + a.w * b.w;
        }
        if (t < 64) us[k] = s; else vs[k] = s;
    }

    // stage x tile (coalesced float4)
    #pragma unroll
    for (int ch = 0; ch < 4; ++ch) {
        int idx = ch * 256 + t;              // 0..1023
        int row = idx >> 7, c4 = idx & 127;
        xs4[row * 128 + c4] = ((const float4*)(x + (size_t)(i0 + row) * KD))[c4];
    }
    __syncthreads();

    const int tx = t & 15, w = (t >> 4) & 7, kh = t >> 7;
    const int c = tx * 4;
    float4 acc = {0.f, 0.f, 0.f, 0.f};
    const float* xrow = xs + w * KD + kh * 256;
    const float* Wp   = W + (size_t)(kh * 256) * DD + c;
    #pragma unroll 8
    for (int k = 0; k < 256; ++k) {
        float  xv = xrow[k];
        float4 wv = *(const float4*)(Wp + (size_t)k * DD);
        acc.x += xv * wv.x; acc.y += xv * wv.y;
        acc.z += xv * wv.z; acc.w += xv * wv.w;
    }
    if (kh) part[t - 128] = acc;
    __syncthreads();
    if (t < 128) {
        float4 p = part[t];
        acc.x += p.x; acc.y += p.y; acc.z += p.z; acc.w += p.w;
        const int row = i0 + w;

        union { unsigned short s[4]; uint2 v; } zb, zwb;
        zb.s[0] = f2bf(acc.x); zb.s[1] = f2bf(acc.y);
        zb.s[2] = f2bf(acc.z); zb.s[3] = f2bf(acc.w);
        *(uint2*)(Zb + (size_t)row * DD + c) = zb.v;

        float4 w3b = *(const float4*)(W3 + DD + c);
        zwb.s[0] = f2bf(acc.x * w3b.x); zwb.s[1] = f2bf(acc.y * w3b.y);
        zwb.s[2] = f2bf(acc.z * w3b.z); zwb.s[3] = f2bf(acc.w * w3b.w);
        *(uint2*)(ZWb + (size_t)row * DD + c) = zwb.v;

        float4 rz = {fmaxf(acc.x, 0.f), fmaxf(acc.y, 0.f),
                     fmaxf(acc.z, 0.f), fmaxf(acc.w, 0.f)};
        float4 u4 = *(const float4*)(us + c);
        float4 v4 = *(const float4*)(vs + c);
        float pa = rz.x * u4.x + rz.y * u4.y + rz.z * u4.z + rz.w * u4.w;
        float pb = rz.x * v4.x + rz.y * v4.y + rz.z * v4.z + rz.w * v4.w;
        #pragma unroll
        for (int m = 1; m < 16; m <<= 1) {
            pa += __shfl_xor(pa, m, 64);
            pb += __shfl_xor(pb, m, 64);
        }
        if (tx == 0) { A[row] = pa; Bv[row] = pb; }
    }
}

// ---------------------------------------------------------------------------
// mainkern: grid (32,32) x 256 threads; 64x64 tile/block via bf16 MFMA.
// out[i,j] = sig(sig(A[i] + Bv[j] + Zb[i,:]·ZWb[j,:])). Outer sigmoid as
// cubic Taylor (input confined to (0,1), max err ~3e-4).
// ---------------------------------------------------------------------------
__global__ __launch_bounds__(256) void mainkern(
    const unsigned short* __restrict__ Zb, const unsigned short* __restrict__ ZWb,
    const float* __restrict__ A, const float* __restrict__ Bv,
    float* __restrict__ out)
{
    __shared__ unsigned short sZ[64 * LSTR + 8];
    __shared__ unsigned short sW[64 * LSTR + 8];
    __shared__ float sA[64], sB[64];
    const int t  = threadIdx.x;
    const int i0 = blockIdx.y * 64, j0 = blockIdx.x * 64;

    if (t < 64)       sA[t]      = A[i0 + t];
    else if (t < 128) sB[t - 64] = Bv[j0 + t - 64];

    // stage 64x64 bf16 tiles, stride-72 padded (bank-balanced b128 writes)
    #pragma unroll
    for (int ch = 0; ch < 2; ++ch) {
        int idx = ch * 256 + t;              // 0..511
        int row = idx >> 3, c8 = idx & 7;    // 8 x 16B chunks per row
        uint4 g = ((const uint4*)(Zb  + (size_t)(i0 + row) * DD))[c8];
        *(uint4*)(sZ + row * LSTR + c8 * 8) = g;
        uint4 h = ((const uint4*)(ZWb + (size_t)(j0 + row) * DD))[c8];
        *(uint4*)(sW + row * LSTR + c8 * 8) = h;
    }
    __syncthreads();

    const int lane = t & 63, w = t >> 6;     // wave w owns rows 16w..16w+15
    const int m = lane & 15, quad = lane >> 4;

    // A frags: A[m][k=quad*8+j], two K-chunks (0..31, 32..63)
    bf16x8 a0 = *(const bf16x8*)(sZ + (16 * w + m) * LSTR + quad * 8);
    bf16x8 a1 = *(const bf16x8*)(sZ + (16 * w + m) * LSTR + 32 + quad * 8);

    f32x4 acc[4];
    #pragma unroll
    for (int t4 = 0; t4 < 4; ++t4) {
        bf16x8 b0 = *(const bf16x8*)(sW + (16 * t4 + m) * LSTR + quad * 8);
        bf16x8 b1 = *(const bf16x8*)(sW + (16 * t4 + m) * LSTR + 32 + quad * 8);
        f32x4 c = {0.f, 0.f, 0.f, 0.f};
        c = __builtin_amdgcn_mfma_f32_16x16x32_bf16(a0, b0, c, 0, 0, 0);
        c = __builtin_amdgcn_mfma_f32_16x16x32_bf16(a1, b1, c, 0, 0, 0);
        acc[t4] = c;
    }

    // epilogue: C layout col=lane&15, row=quad*4+reg
    #pragma unroll
    for (int t4 = 0; t4 < 4; ++t4) {
        const int j  = j0 + 16 * t4 + m;
        const float bj = sB[16 * t4 + m];
        #pragma unroll
        for (int r = 0; r < 4; ++r) {
            const int il = 16 * w + quad * 4 + r;
            float s  = sA[il] + bj + acc[t4][r];
            float y  = sigf(s);                       // inner sigmoid, exact
            float tt = y - 0.5f;                      // outer: cubic Taylor
            float o  = 0.6224593f +
                       tt * (0.2350037f + tt * (-0.0287786f + tt * (-0.0160594f)));
            out[(size_t)(i0 + il) * NDIM + j] = o;
        }
    }
}

extern "C" void kernel_launch(void* const* d_in, const int* in_sizes, int n_in,
                              void* d_out, int out_size, void* d_ws, size_t ws_size,
                              hipStream_t stream)
{
    const float* x  = (const float*)d_in[0];   // 2048 x 512
    const float* W  = (const float*)d_in[1];   // 512 x 64
    const float* W2 = (const float*)d_in[2];   // 128 x 64
    const float* W3 = (const float*)d_in[3];   // 128 x 1
    float* out = (float*)d_out;                // 2048 x 2048 f32

    char* ws = (char*)d_ws;
    float* A  = (float*)ws;                              // 2048 f32
    float* Bv = (float*)(ws + 8192);                     // 2048 f32
    unsigned short* Zb  = (unsigned short*)(ws + 16384);               // 2048x64 bf16
    unsigned short* ZWb = (unsigned short*)(ws + 16384 + NDIM * DD * 2);

    zkern<<<dim3(256), dim3(256), 0, stream>>>(x, W, W2, W3, A, Bv, Zb, ZWb);
    mainkern<<<dim3(32, 32), dim3(256), 0, stream>>>(Zb, ZWb, A, Bv, out);
}

// Round 3
// 78.064 us; speedup vs baseline: 1.2939x; 1.0315x over previous
//
#include <hip/hip_runtime.h>

#define NDIM 2048
#define KD 512
#define DD 64
#define LSTR 72   // mainkern LDS row stride in bf16 (144 B): 16B-aligned, bank-balanced

typedef short bf16x8 __attribute__((ext_vector_type(8)));
typedef float f32x4  __attribute__((ext_vector_type(4)));

__device__ __forceinline__ float sigf(float x) {
    return __builtin_amdgcn_rcpf(1.0f + __builtin_amdgcn_exp2f(x * -1.44269504088896f));
}
__device__ __forceinline__ unsigned short f2bf(float f) {
    union { float f; unsigned u; } c; c.f = f;
    unsigned r = c.u + 0x7FFF + ((c.u >> 16) & 1);   // RNE
    return (unsigned short)(r >> 16);
}

// ---------------------------------------------------------------------------
// zkern: 512 blocks x 256 threads, 4 rows/block, split-K(4).
// 2 blocks/CU -> 8 waves/CU for latency hiding; W quarter (32KB) fits L1.
// Emits A=relu(z)@u, Bv=relu(z)@v (f32), Zb=bf16(z), ZWb=bf16(z*w3b).
// ---------------------------------------------------------------------------
__global__ __launch_bounds__(256) void zkern(
    const float* __restrict__ x, const float* __restrict__ W,
    const float* __restrict__ W2, const float* __restrict__ W3,
    float* __restrict__ A, float* __restrict__ Bv,
    unsigned short* __restrict__ Zb, unsigned short* __restrict__ ZWb)
{
    __shared__ float4 xs4[4 * 128];          // 4 rows x 512 f32 = 8 KB
    __shared__ float  us[64], vs[64];
    __shared__ float4 part[3 * 64];          // split-K partials for kh=1..3
    const int t  = threadIdx.x;
    const int i0 = blockIdx.x * 4;

    // u = W2[:64]@w3a (wave0), v = W2[64:]@w3a (wave1)
    if (t < 128) {
        const int k = t & 63;
        const float* wrow = W2 + (size_t)(t < 64 ? k : 64 + k) * 64;
        float s = 0.f;
        #pragma unroll
        for (int n4 = 0; n4 < 16; ++n4) {
            float4 a = ((const float4*)wrow)[n4];
            float4 b = ((const float4*)W3)[n4];
            s += a.x * b.x + a.y * b.y + a.z * b.z + a.w * b.w;
        }
        if (t < 64) us[k] = s; else vs[k] = s;
    }

    // stage x tile (4 x 512 f32, coalesced float4)
    #pragma unroll
    for (int ch = 0; ch < 2; ++ch) {
        int idx = ch * 256 + t;              // 0..511
        int row = idx >> 7, c4 = idx & 127;
        xs4[row * 128 + c4] = ((const float4*)(x + (size_t)(i0 + row) * KD))[c4];
    }
    __syncthreads();

    const int tx = t & 15, rw = (t >> 4) & 3, kh = t >> 6;   // kh wave-uniform
    const int c = tx * 4;
    float4 acc = {0.f, 0.f, 0.f, 0.f};
    const float* xrow = (const float*)xs4 + rw * KD + kh * 128;
    const float* Wp   = W + (size_t)(kh * 128) * DD + c;
    #pragma unroll 8
    for (int k = 0; k < 128; ++k) {
        float  xv = xrow[k];                                   // LDS broadcast
        float4 wv = *(const float4*)(Wp + (size_t)k * DD);     // L1-resident
        acc.x += xv * wv.x; acc.y += xv * wv.y;
        acc.z += xv * wv.z; acc.w += xv * wv.w;
    }
    if (kh) part[(kh - 1) * 64 + rw * 16 + tx] = acc;
    __syncthreads();

    if (t < 64) {
        float4 p0 = part[t], p1 = part[64 + t], p2 = part[128 + t];
        acc.x += p0.x + p1.x + p2.x;
        acc.y += p0.y + p1.y + p2.y;
        acc.z += p0.z + p1.z + p2.z;
        acc.w += p0.w + p1.w + p2.w;
        const int row = i0 + rw;

        union { unsigned short s[4]; uint2 v; } zb, zwb;
        zb.s[0] = f2bf(acc.x); zb.s[1] = f2bf(acc.y);
        zb.s[2] = f2bf(acc.z); zb.s[3] = f2bf(acc.w);
        *(uint2*)(Zb + (size_t)row * DD + c) = zb.v;

        float4 w3b = *(const float4*)(W3 + DD + c);
        zwb.s[0] = f2bf(acc.x * w3b.x); zwb.s[1] = f2bf(acc.y * w3b.y);
        zwb.s[2] = f2bf(acc.z * w3b.z); zwb.s[3] = f2bf(acc.w * w3b.w);
        *(uint2*)(ZWb + (size_t)row * DD + c) = zwb.v;

        float4 rz = {fmaxf(acc.x, 0.f), fmaxf(acc.y, 0.f),
                     fmaxf(acc.z, 0.f), fmaxf(acc.w, 0.f)};
        float4 u4 = *(const float4*)(us + c);
        float4 v4 = *(const float4*)(vs + c);
        float pa = rz.x * u4.x + rz.y * u4.y + rz.z * u4.z + rz.w * u4.w;
        float pb = rz.x * v4.x + rz.y * v4.y + rz.z * v4.z + rz.w * v4.w;
        #pragma unroll
        for (int m = 1; m < 16; m <<= 1) {    // reduce within 16-lane groups
            pa += __shfl_xor(pa, m, 64);
            pb += __shfl_xor(pb, m, 64);
        }
        if (tx == 0) { A[row] = pa; Bv[row] = pb; }
    }
}

// ---------------------------------------------------------------------------
// mainkern: grid (32,32) x 256 threads; 64x64 tile/block via bf16 MFMA.
// out[i,j] = sig(sig(A[i] + Bv[j] + Zb[i,:]·ZWb[j,:])). Outer sigmoid as
// cubic Taylor (input confined to (0,1), max err ~3e-4). HBM-write-bound.
// ---------------------------------------------------------------------------
__global__ __launch_bounds__(256) void mainkern(
    const unsigned short* __restrict__ Zb, const unsigned short* __restrict__ ZWb,
    const float* __restrict__ A, const float* __restrict__ Bv,
    float* __restrict__ out)
{
    __shared__ unsigned short sZ[64 * LSTR + 8];
    __shared__ unsigned short sW[64 * LSTR + 8];
    __shared__ float sA[64], sB[64];
    const int t  = threadIdx.x;
    const int i0 = blockIdx.y * 64, j0 = blockIdx.x * 64;

    if (t < 64)       sA[t]      = A[i0 + t];
    else if (t < 128) sB[t - 64] = Bv[j0 + t - 64];

    // stage 64x64 bf16 tiles, stride-72 padded (bank-balanced b128 writes)
    #pragma unroll
    for (int ch = 0; ch < 2; ++ch) {
        int idx = ch * 256 + t;              // 0..511
        int row = idx >> 3, c8 = idx & 7;    // 8 x 16B chunks per row
        uint4 g = ((const uint4*)(Zb  + (size_t)(i0 + row) * DD))[c8];
        *(uint4*)(sZ + row * LSTR + c8 * 8) = g;
        uint4 h = ((const uint4*)(ZWb + (size_t)(j0 + row) * DD))[c8];
        *(uint4*)(sW + row * LSTR + c8 * 8) = h;
    }
    __syncthreads();

    const int lane = t & 63, w = t >> 6;     // wave w owns rows 16w..16w+15
    const int m = lane & 15, quad = lane >> 4;

    // A frags: A[m][k=quad*8+j], two K-chunks (0..31, 32..63)
    bf16x8 a0 = *(const bf16x8*)(sZ + (16 * w + m) * LSTR + quad * 8);
    bf16x8 a1 = *(const bf16x8*)(sZ + (16 * w + m) * LSTR + 32 + quad * 8);

    f32x4 acc[4];
    #pragma unroll
    for (int t4 = 0; t4 < 4; ++t4) {
        bf16x8 b0 = *(const bf16x8*)(sW + (16 * t4 + m) * LSTR + quad * 8);
        bf16x8 b1 = *(const bf16x8*)(sW + (16 * t4 + m) * LSTR + 32 + quad * 8);
        f32x4 c = {0.f, 0.f, 0.f, 0.f};
        c = __builtin_amdgcn_mfma_f32_16x16x32_bf16(a0, b0, c, 0, 0, 0);
        c = __builtin_amdgcn_mfma_f32_16x16x32_bf16(a1, b1, c, 0, 0, 0);
        acc[t4] = c;
    }

    // epilogue: C layout col=lane&15, row=quad*4+reg
    #pragma unroll
    for (int t4 = 0; t4 < 4; ++t4) {
        const int j  = j0 + 16 * t4 + m;
        const float bj = sB[16 * t4 + m];
        #pragma unroll
        for (int r = 0; r < 4; ++r) {
            const int il = 16 * w + quad * 4 + r;
            float s  = sA[il] + bj + acc[t4][r];
            float y  = sigf(s);                       // inner sigmoid, exact
            float tt = y - 0.5f;                      // outer: cubic Taylor
            float o  = 0.6224593f +
                       tt * (0.2350037f + tt * (-0.0287786f + tt * (-0.0160594f)));
            out[(size_t)(i0 + il) * NDIM + j] = o;
        }
    }
}

extern "C" void kernel_launch(void* const* d_in, const int* in_sizes, int n_in,
                              void* d_out, int out_size, void* d_ws, size_t ws_size,
                              hipStream_t stream)
{
    const float* x  = (const float*)d_in[0];   // 2048 x 512
    const float* W  = (const float*)d_in[1];   // 512 x 64
    const float* W2 = (const float*)d_in[2];   // 128 x 64
    const float* W3 = (const float*)d_in[3];   // 128 x 1
    float* out = (float*)d_out;                // 2048 x 2048 f32

    char* ws = (char*)d_ws;
    float* A  = (float*)ws;                              // 2048 f32
    float* Bv = (float*)(ws + 8192);                     // 2048 f32
    unsigned short* Zb  = (unsigned short*)(ws + 16384);               // 2048x64 bf16
    unsigned short* ZWb = (unsigned short*)(ws + 16384 + NDIM * DD * 2);

    zkern<<<dim3(512), dim3(256), 0, stream>>>(x, W, W2, W3, A, Bv, Zb, ZWb);
    mainkern<<<dim3(32, 32), dim3(256), 0, stream>>>(Zb, ZWb, A, Bv, out);
}

// Round 4
// 77.822 us; speedup vs baseline: 1.2979x; 1.0031x over previous
//
#include <hip/hip_runtime.h>

#define NDIM 2048
#define KD 512
#define DD 64
#define LSTR 72   // mainkern LDS row stride in bf16 (144 B): 16B-aligned, bank-balanced

typedef short bf16x8 __attribute__((ext_vector_type(8)));
typedef float f32x4  __attribute__((ext_vector_type(4)));

__device__ __forceinline__ float sigf(float x) {
    return __builtin_amdgcn_rcpf(1.0f + __builtin_amdgcn_exp2f(x * -1.44269504088896f));
}
__device__ __forceinline__ unsigned short f2bf(float f) {
    union { float f; unsigned u; } c; c.f = f;
    unsigned r = c.u + 0x7FFF + ((c.u >> 16) & 1);   // RNE
    return (unsigned short)(r >> 16);
}

// ---------------------------------------------------------------------------
// zkern: 512 blocks x 256 threads, 4 rows/block, split-K(4).
// 2 blocks/CU -> 8 waves/CU for latency hiding; W quarter (32KB) fits L1.
// Emits A=relu(z)@u, Bv=relu(z)@v (f32), Zb=bf16(z), ZWb=bf16(z*w3b).
// ---------------------------------------------------------------------------
__global__ __launch_bounds__(256) void zkern(
    const float* __restrict__ x, const float* __restrict__ W,
    const float* __restrict__ W2, const float* __restrict__ W3,
    float* __restrict__ A, float* __restrict__ Bv,
    unsigned short* __restrict__ Zb, unsigned short* __restrict__ ZWb)
{
    __shared__ float4 xs4[4 * 128];          // 4 rows x 512 f32 = 8 KB
    __shared__ float  us[64], vs[64];
    __shared__ float4 part[3 * 64];          // split-K partials for kh=1..3
    const int t  = threadIdx.x;
    const int i0 = blockIdx.x * 4;

    // u = W2[:64]@w3a (wave0), v = W2[64:]@w3a (wave1)
    if (t < 128) {
        const int k = t & 63;
        const float* wrow = W2 + (size_t)(t < 64 ? k : 64 + k) * 64;
        float s = 0.f;
        #pragma unroll
        for (int n4 = 0; n4 < 16; ++n4) {
            float4 a = ((const float4*)wrow)[n4];
            float4 b = ((const float4*)W3)[n4];
            s += a.x * b.x + a.y * b.y + a.z * b.z + a.w * b.w;
        }
        if (t < 64) us[k] = s; else vs[k] = s;
    }

    // stage x tile (4 x 512 f32, coalesced float4)
    #pragma unroll
    for (int ch = 0; ch < 2; ++ch) {
        int idx = ch * 256 + t;              // 0..511
        int row = idx >> 7, c4 = idx & 127;
        xs4[row * 128 + c4] = ((const float4*)(x + (size_t)(i0 + row) * KD))[c4];
    }
    __syncthreads();

    const int tx = t & 15, rw = (t >> 4) & 3, kh = t >> 6;   // kh wave-uniform
    const int c = tx * 4;
    float4 acc = {0.f, 0.f, 0.f, 0.f};
    const float* xrow = (const float*)xs4 + rw * KD + kh * 128;
    const float* Wp   = W + (size_t)(kh * 128) * DD + c;
    #pragma unroll 8
    for (int k = 0; k < 128; ++k) {
        float  xv = xrow[k];                                   // LDS broadcast
        float4 wv = *(const float4*)(Wp + (size_t)k * DD);     // L1-resident
        acc.x += xv * wv.x; acc.y += xv * wv.y;
        acc.z += xv * wv.z; acc.w += xv * wv.w;
    }
    if (kh) part[(kh - 1) * 64 + rw * 16 + tx] = acc;
    __syncthreads();

    if (t < 64) {
        float4 p0 = part[t], p1 = part[64 + t], p2 = part[128 + t];
        acc.x += p0.x + p1.x + p2.x;
        acc.y += p0.y + p1.y + p2.y;
        acc.z += p0.z + p1.z + p2.z;
        acc.w += p0.w + p1.w + p2.w;
        const int row = i0 + rw;

        union { unsigned short s[4]; uint2 v; } zb, zwb;
        zb.s[0] = f2bf(acc.x); zb.s[1] = f2bf(acc.y);
        zb.s[2] = f2bf(acc.z); zb.s[3] = f2bf(acc.w);
        *(uint2*)(Zb + (size_t)row * DD + c) = zb.v;

        float4 w3b = *(const float4*)(W3 + DD + c);
        zwb.s[0] = f2bf(acc.x * w3b.x); zwb.s[1] = f2bf(acc.y * w3b.y);
        zwb.s[2] = f2bf(acc.z * w3b.z); zwb.s[3] = f2bf(acc.w * w3b.w);
        *(uint2*)(ZWb + (size_t)row * DD + c) = zwb.v;

        float4 rz = {fmaxf(acc.x, 0.f), fmaxf(acc.y, 0.f),
                     fmaxf(acc.z, 0.f), fmaxf(acc.w, 0.f)};
        float4 u4 = *(const float4*)(us + c);
        float4 v4 = *(const float4*)(vs + c);
        float pa = rz.x * u4.x + rz.y * u4.y + rz.z * u4.z + rz.w * u4.w;
        float pb = rz.x * v4.x + rz.y * v4.y + rz.z * v4.z + rz.w * v4.w;
        #pragma unroll
        for (int m = 1; m < 16; m <<= 1) {    // reduce within 16-lane groups
            pa += __shfl_xor(pa, m, 64);
            pb += __shfl_xor(pb, m, 64);
        }
        if (tx == 0) { A[row] = pa; Bv[row] = pb; }
    }
}

// ---------------------------------------------------------------------------
// mainkern: grid (32,32) x 256 threads; 64x64 tile/block via bf16 MFMA.
// out[i,j] = sig(sig(A[i] + Bv[j] + Zb[i,:]·ZWb[j,:])). Outer sigmoid as
// cubic Taylor (input confined to (0,1), max err ~3e-4). HBM-write-bound;
// output streamed with non-temporal stores (write-once, keep L2 for Zb/ZWb).
// ---------------------------------------------------------------------------
__global__ __launch_bounds__(256) void mainkern(
    const unsigned short* __restrict__ Zb, const unsigned short* __restrict__ ZWb,
    const float* __restrict__ A, const float* __restrict__ Bv,
    float* __restrict__ out)
{
    __shared__ unsigned short sZ[64 * LSTR + 8];
    __shared__ unsigned short sW[64 * LSTR + 8];
    __shared__ float sA[64], sB[64];
    const int t  = threadIdx.x;
    const int i0 = blockIdx.y * 64, j0 = blockIdx.x * 64;

    if (t < 64)       sA[t]      = A[i0 + t];
    else if (t < 128) sB[t - 64] = Bv[j0 + t - 64];

    // stage 64x64 bf16 tiles, stride-72 padded (bank-balanced b128 writes)
    #pragma unroll
    for (int ch = 0; ch < 2; ++ch) {
        int idx = ch * 256 + t;              // 0..511
        int row = idx >> 3, c8 = idx & 7;    // 8 x 16B chunks per row
        uint4 g = ((const uint4*)(Zb  + (size_t)(i0 + row) * DD))[c8];
        *(uint4*)(sZ + row * LSTR + c8 * 8) = g;
        uint4 h = ((const uint4*)(ZWb + (size_t)(j0 + row) * DD))[c8];
        *(uint4*)(sW + row * LSTR + c8 * 8) = h;
    }
    __syncthreads();

    const int lane = t & 63, w = t >> 6;     // wave w owns rows 16w..16w+15
    const int m = lane & 15, quad = lane >> 4;

    // A frags: A[m][k=quad*8+j], two K-chunks (0..31, 32..63)
    bf16x8 a0 = *(const bf16x8*)(sZ + (16 * w + m) * LSTR + quad * 8);
    bf16x8 a1 = *(const bf16x8*)(sZ + (16 * w + m) * LSTR + 32 + quad * 8);

    f32x4 acc[4];
    #pragma unroll
    for (int t4 = 0; t4 < 4; ++t4) {
        bf16x8 b0 = *(const bf16x8*)(sW + (16 * t4 + m) * LSTR + quad * 8);
        bf16x8 b1 = *(const bf16x8*)(sW + (16 * t4 + m) * LSTR + 32 + quad * 8);
        f32x4 c = {0.f, 0.f, 0.f, 0.f};
        c = __builtin_amdgcn_mfma_f32_16x16x32_bf16(a0, b0, c, 0, 0, 0);
        c = __builtin_amdgcn_mfma_f32_16x16x32_bf16(a1, b1, c, 0, 0, 0);
        acc[t4] = c;
    }

    // epilogue: C layout col=lane&15, row=quad*4+reg; nt streaming stores
    #pragma unroll
    for (int t4 = 0; t4 < 4; ++t4) {
        const int j   = j0 + 16 * t4 + m;
        const float bj = sB[16 * t4 + m];
        float* op = out + (size_t)(i0 + 16 * w + quad * 4) * NDIM + j;
        #pragma unroll
        for (int r = 0; r < 4; ++r) {
            const float ab = sA[16 * w + quad * 4 + r] + bj;
            float s  = ab + acc[t4][r];
            float y  = sigf(s);                       // inner sigmoid, exact
            float tt = y - 0.5f;                      // outer: cubic Taylor
            float o  = 0.6224593f +
                       tt * (0.2350037f + tt * (-0.0287786f + tt * (-0.0160594f)));
            __builtin_nontemporal_store(o, op);
            op += NDIM;
        }
    }
}

extern "C" void kernel_launch(void* const* d_in, const int* in_sizes, int n_in,
                              void* d_out, int out_size, void* d_ws, size_t ws_size,
                              hipStream_t stream)
{
    const float* x  = (const float*)d_in[0];   // 2048 x 512
    const float* W  = (const float*)d_in[1];   // 512 x 64
    const float* W2 = (const float*)d_in[2];   // 128 x 64
    const float* W3 = (const float*)d_in[3];   // 128 x 1
    float* out = (float*)d_out;                // 2048 x 2048 f32

    char* ws = (char*)d_ws;
    float* A  = (float*)ws;                              // 2048 f32
    float* Bv = (float*)(ws + 8192);                     // 2048 f32
    unsigned short* Zb  = (unsigned short*)(ws + 16384);               // 2048x64 bf16
    unsigned short* ZWb = (unsigned short*)(ws + 16384 + NDIM * DD * 2);

    zkern<<<dim3(512), dim3(256), 0, stream>>>(x, W, W2, W3, A, Bv, Zb, ZWb);
    mainkern<<<dim3(32, 32), dim3(256), 0, stream>>>(Zb, ZWb, A, Bv, out);
}